// Round 7
// baseline (1025.461 us; speedup 1.0000x reference)
//
#include <hip/hip_runtime.h>
#include <stdint.h>

typedef short bf16x8 __attribute__((ext_vector_type(8)));
typedef short s4 __attribute__((ext_vector_type(4)));
typedef float f32x4 __attribute__((ext_vector_type(4)));

#define NPOS 65536  // B*L = 64*1024
#define MB (1024ull * 1024ull)
#define SK_PIECE 2097152  // shorts per 4MB piece of the in-place skip output

__device__ __forceinline__ unsigned short f32_bf16(float f) {
    union { float f; unsigned u; } v; v.f = f;
    unsigned u = v.u;
    u += 0x7fffu + ((u >> 16) & 1u);
    return (unsigned short)(u >> 16);
}

// 4 floats -> 4 bf16 via v_cvt_pk_bf16_f32 (RNE)
__device__ __forceinline__ s4 pk4_bf16(float a, float b, float c, float d) {
    union { unsigned u[2]; s4 v; } r;
    asm("v_cvt_pk_bf16_f32 %0, %1, %2" : "=v"(r.u[0]) : "v"(a), "v"(b));
    asm("v_cvt_pk_bf16_f32 %0, %1, %2" : "=v"(r.u[1]) : "v"(c), "v"(d));
    return r.v;
}

__device__ __forceinline__ bf16x8 pk8_bf16(const float* v) {
    union { unsigned u[4]; bf16x8 x; } r;
    asm("v_cvt_pk_bf16_f32 %0, %1, %2" : "=v"(r.u[0]) : "v"(v[0]), "v"(v[1]));
    asm("v_cvt_pk_bf16_f32 %0, %1, %2" : "=v"(r.u[1]) : "v"(v[2]), "v"(v[3]));
    asm("v_cvt_pk_bf16_f32 %0, %1, %2" : "=v"(r.u[2]) : "v"(v[4]), "v"(v[5]));
    asm("v_cvt_pk_bf16_f32 %0, %1, %2" : "=v"(r.u[3]) : "v"(v[6]), "v"(v[7]));
    return r.x;
}

// fallback: encode ws_size (MiB) into output so a failing run tells us the budget
__global__ void ws_probe_k(float* __restrict__ out, float mib) {
    int i = blockIdx.x * 256 + threadIdx.x;
    if (i < 16384) out[i] = mib;
}

// ---- repack filter+gate weights -> bf16, MFMA-A rows PERMUTED so the conv
// C-fragment lands in B-fragment layout: A-row m of block mt holds
// oc = (m>>2)*8 + mt*4 + (m&3).  Blocks: rq>>4 = {f-mt0, f-mt1, g-mt0, g-mt1}.
__global__ void repack_fgw_k(const float* __restrict__ fw,
                             const float* __restrict__ gw,
                             unsigned short* __restrict__ out) {
    int idx = blockIdx.x * 256 + threadIdx.x;  // < 40*3*64*32 = 245760
    int ic = idx & 31;
    int r1 = idx >> 5;
    int rq = r1 & 63;
    int r2 = r1 >> 6;      // i*3 + k
    int k  = r2 % 3;
    int i  = r2 / 3;
    int part = rq >> 4;
    int m = rq & 15;
    int oc = ((m >> 2) << 3) + ((part & 1) << 2) + (m & 3);
    const float* src = (part < 2) ? fw : gw;
    out[idx] = f32_bf16(src[(((i * 32 + oc) * 32 + ic) * 3) + k]);
}

// ---- repack skip weights fp32 -> bf16, same layout [40][256][32]
__global__ void repack_sw_k(const float* __restrict__ sw,
                            unsigned short* __restrict__ out) {
    int idx = blockIdx.x * 256 + threadIdx.x;  // < 40*256*32 = 327680
    out[idx] = f32_bf16(sw[idx]);
}

// ---- repack residual weights -> bf16 with the same row permutation:
// A-row m of block rt holds oc = (m>>2)*8 + rt*4 + (m&3)
__global__ void repack_rw_k(const float* __restrict__ rw,
                            unsigned short* __restrict__ out) {
    int idx = blockIdx.x * 256 + threadIdx.x;  // < 40*32*32 = 40960
    int ic = idx & 31;
    int r1 = idx >> 5;
    int rq = r1 & 31;
    int i  = r1 >> 5;
    int rt = rq >> 4, m = rq & 15;
    int oc = ((m >> 2) << 3) + (rt << 2) + (m & 3);
    out[idx] = f32_bf16(rw[(i * 32 + oc) * 32 + ic]);
}

#define MFMA16(A, B, C) __builtin_amdgcn_mfma_f32_16x16x32_bf16(A, B, C, 0, 0, 0)

// ============================================================================
// Row-resident fused WaveNet v3: 64 blocks x 512 thr (8 waves, 8 groups ea).
// Hybrid of v1 (round 5: 2 blocks/CU barrier overlap) and v2 (round 6:
// permuted weights -> register-direct gating->xg/res, no stage buffer).
// Single 64KB x buffer, 2 barriers/layer; 2 blocks/CU hide barrier drain.
// ============================================================================
__global__ __launch_bounds__(512, 4) void wavenet_rows_k(
    const float* __restrict__ in,               // [64][2][1024]
    const float* __restrict__ stw,              // [32][2]
    const unsigned short* __restrict__ fgw_all, // [40][3][64][32] permuted
    const unsigned short* __restrict__ rwb_all, // [40][32][32] permuted
    unsigned short* __restrict__ xg_all)        // [40][65536][32] bf16
{
    __shared__ __align__(16) unsigned short xb16[1024 * 32];   // 64 KB
    const int tid = threadIdx.x;
    const int w = tid >> 6, lane = tid & 63;
    const int quad = lane >> 4, l15 = lane & 15;
    const int b = blockIdx.x;
    const f32x4 zero = {0.f, 0.f, 0.f, 0.f};

    float xreg[8][8];   // ch = quad*8 + j at pos (w*8+g)*16 + l15

    // ---- start conv (2 -> 32 ch) into registers + LDS
    {
        float s0[8], s1[8];
#pragma unroll
        for (int j = 0; j < 8; ++j) {
            int c = quad * 8 + j;
            s0[j] = stw[c * 2 + 0];
            s1[j] = stw[c * 2 + 1];
        }
#pragma unroll
        for (int g = 0; g < 8; ++g) {
            int t = (w * 8 + g) * 16 + l15;
            float i0 = in[b * 2048 + t];
            float i1 = in[b * 2048 + 1024 + t];
#pragma unroll
            for (int j = 0; j < 8; ++j) xreg[g][j] = s0[j] * i0 + s1[j] * i1;
            *(bf16x8*)(xb16 + t * 32 + ((quad ^ (t & 3)) * 8)) = pk8_bf16(xreg[g]);
        }
    }
    __syncthreads();

#pragma unroll 1
    for (int i = 0; i < 40; ++i) {
        const int d = 1 << (i % 10);
        const unsigned short* fgw = fgw_all + (size_t)i * 6144;
        unsigned short* xg = xg_all + (size_t)i * ((size_t)NPOS * 32)
                                    + (size_t)b * (1024 * 32);
        const bool dores = (i < 39);

        // preload weights (L2-hot)
        bf16x8 wf[3][2], wg[3][2];
#pragma unroll
        for (int k = 0; k < 3; ++k) {
            const unsigned short* wb = fgw + k * 2048;
#pragma unroll
            for (int mt = 0; mt < 2; ++mt) {
                wf[k][mt] = *(const bf16x8*)(wb + (mt * 16 + l15) * 32 + quad * 8);
                wg[k][mt] = *(const bf16x8*)(wb + ((mt + 2) * 16 + l15) * 32 + quad * 8);
            }
        }
        bf16x8 wr0, wr1;
        if (dores) {
            const unsigned short* rwb = rwb_all + (size_t)i * 1024;
            wr0 = *(const bf16x8*)(rwb + l15 * 32 + quad * 8);
            wr1 = *(const bf16x8*)(rwb + (16 + l15) * 32 + quad * 8);
        }

#pragma unroll
        for (int g = 0; g < 8; ++g) {
            const int tc = (w * 8 + g) * 16 + l15;

            bf16x8 zz;
#pragma unroll
            for (int j = 0; j < 8; ++j) zz[j] = 0;

            f32x4 accf[2] = {zero, zero};
            f32x4 accg[2] = {zero, zero};
            {   // left tap
                int ts = tc - d, tm = ts & 1023;
                bf16x8 rv = *(const bf16x8*)(xb16 + tm * 32 + ((quad ^ (tm & 3)) * 8));
                bf16x8 b0 = (ts >= 0) ? rv : zz;
#pragma unroll
                for (int mt = 0; mt < 2; ++mt) {
                    accf[mt] = MFMA16(wf[0][mt], b0, accf[mt]);
                    accg[mt] = MFMA16(wg[0][mt], b0, accg[mt]);
                }
            }
            {   // center tap
                bf16x8 b1 = *(const bf16x8*)(xb16 + tc * 32 + ((quad ^ (tc & 3)) * 8));
#pragma unroll
                for (int mt = 0; mt < 2; ++mt) {
                    accf[mt] = MFMA16(wf[1][mt], b1, accf[mt]);
                    accg[mt] = MFMA16(wg[1][mt], b1, accg[mt]);
                }
            }
            {   // right tap
                int ts = tc + d, tm = ts & 1023;
                bf16x8 rv = *(const bf16x8*)(xb16 + tm * 32 + ((quad ^ (tm & 3)) * 8));
                bf16x8 b2 = (ts < 1024) ? rv : zz;
#pragma unroll
                for (int mt = 0; mt < 2; ++mt) {
                    accf[mt] = MFMA16(wf[2][mt], b2, accf[mt]);
                    accg[mt] = MFMA16(wg[2][mt], b2, accg[mt]);
                }
            }

            // gating: tanh(f)*sigmoid(g) = (a-1) * rcp((a+1)(1+c)), 3 trans
            float gv[8];
#pragma unroll
            for (int mt = 0; mt < 2; ++mt)
#pragma unroll
                for (int r = 0; r < 4; ++r) {
                    float fv = accf[mt][r], gg = accg[mt][r];
                    fv = fminf(fmaxf(fv, -10.f), 10.f);
                    gg = fminf(fmaxf(gg, -15.f), 15.f);
                    float a = __expf(2.f * fv);
                    float c = __expf(-gg);
                    float rr = __builtin_amdgcn_rcpf((a + 1.f) * (1.f + c));
                    gv[mt * 4 + r] = (a - 1.f) * rr;
                }
            bf16x8 bx = pk8_bf16(gv);   // == xg fragment AND res-B fragment

            // coalesced register->global xg store
            *(bf16x8*)(xg + (size_t)tc * 32 + quad * 8) = bx;

            if (dores) {
                f32x4 a0 = MFMA16(wr0, bx, zero);
                f32x4 a1 = MFMA16(wr1, bx, zero);
#pragma unroll
                for (int r = 0; r < 4; ++r) {
                    xreg[g][r]     += a0[r];
                    xreg[g][4 + r] += a1[r];
                }
            }
        }

        if (dores) {
            __syncthreads();   // all reads of old x done
#pragma unroll
            for (int g = 0; g < 8; ++g) {
                int t = (w * 8 + g) * 16 + l15;
                *(bf16x8*)(xb16 + t * 32 + ((quad ^ (t & 3)) * 8)) = pk8_bf16(xreg[g]);
            }
            __syncthreads();   // new x published
        }
    }
}

// ============================================================================
// skip GEMM v5: B tile staged once per block via global_load_lds (16B), LDS
// double-buffered, slot-swizzled on the GLOBAL SOURCE (inverse of the read
// swizzle) so ds_read_b128 fragment reads are <=2-way bank aliased.
// A (weights) 1-deep register prefetch from L2. XCD-aware block swizzle.
// Output in-place piece layout (unchanged).
// ============================================================================
__global__ __launch_bounds__(256) void skip_gemm_k(
    const unsigned short* __restrict__ xg_all,  // [40][65536][32] bf16
    const unsigned short* __restrict__ swb,     // [40][256][32] bf16
    unsigned short* __restrict__ sk)            // == xg_all base (in-place)
{
    __shared__ __align__(16) unsigned short lds[256 * 72];  // 36 KB; first 4096
                                                            // shorts = 2 B-bufs
    int tid = threadIdx.x;
    int w = tid >> 6, lane = tid & 63;
    int quad = lane >> 4, l15 = lane & 15;
    int pb = (blockIdx.x & 7) * 128 + (blockIdx.x >> 3);   // bijective (1024%8==0)
    int p0 = pb * 64;
    f32x4 zero = {0.f, 0.f, 0.f, 0.f};
    f32x4 acc[4][4];
#pragma unroll
    for (int a = 0; a < 4; ++a)
#pragma unroll
        for (int c = 0; c < 4; ++c) acc[a][c] = zero;

    // staging: slot s (=tid) holds tile unit u = s ^ ((s>>3)&7)  (involution)
    const int gswz = tid ^ ((tid >> 3) & 7);
    // reader: frag (ct,lane): u = (ct*16+l15)*4+quad; slot = u ^ ((u>>3)&7)
    int rslot[4];
#pragma unroll
    for (int ct = 0; ct < 4; ++ct) {
        int u = (ct * 16 + l15) * 4 + quad;
        rslot[ct] = u ^ ((u >> 3) & 7);
    }

    const unsigned short* abase = swb + ((size_t)(w * 64 + l15)) * 32 + quad * 8;

    auto stage = [&](int i, int s) {
        const unsigned short* g = xg_all + ((size_t)i * NPOS + p0) * 32 + gswz * 8;
        unsigned short* l = lds + s * 2048 + w * 512;
        __builtin_amdgcn_global_load_lds(
            (const __attribute__((address_space(1))) unsigned int*)g,
            (__attribute__((address_space(3))) unsigned int*)l, 16, 0, 0);
    };

    stage(0, 0);
    bf16x8 acur[4], anxt[4];
#pragma unroll
    for (int rt = 0; rt < 4; ++rt) acur[rt] = *(const bf16x8*)(abase + rt * 512);

#pragma unroll 2
    for (int i = 0; i < 40; ++i) {
        int cb = i & 1;
        __syncthreads();   // stage(i) landed (vmcnt drained) + old readers done
        if (i + 1 < 40) {
            stage(i + 1, cb ^ 1);
            const unsigned short* an = abase + (size_t)(i + 1) * 8192;
#pragma unroll
            for (int rt = 0; rt < 4; ++rt) anxt[rt] = *(const bf16x8*)(an + rt * 512);
        }
        const unsigned short* bufc = lds + cb * 2048;
        bf16x8 bfr[4];
#pragma unroll
        for (int ct = 0; ct < 4; ++ct) bfr[ct] = *(const bf16x8*)(bufc + rslot[ct] * 8);
#pragma unroll
        for (int rt = 0; rt < 4; ++rt)
#pragma unroll
            for (int ct = 0; ct < 4; ++ct)
                acc[rt][ct] = MFMA16(acur[rt], bfr[ct], acc[rt][ct]);
#pragma unroll
        for (int rt = 0; rt < 4; ++rt) acur[rt] = anxt[rt];
    }

    __syncthreads();   // all waves done with B bufs before epilogue overwrites
#pragma unroll
    for (int rt = 0; rt < 4; ++rt)
#pragma unroll
        for (int ct = 0; ct < 4; ++ct)
#pragma unroll
            for (int r = 0; r < 4; ++r) {
                float v = acc[rt][ct][r];
                v = v > 0.f ? v : 0.f;
                lds[(w * 64 + rt * 16 + quad * 4 + r) * 72 + ct * 16 + l15] = f32_bf16(v);
            }
    __syncthreads();
    {
        size_t pbbase = (size_t)pb * 2048;
#pragma unroll
        for (int j = 0; j < 8; ++j) {
            int idx = tid + 256 * j;      // 2048 16B chunks
            int sc = idx >> 3, tc = idx & 7;
            int4 v = *(const int4*)(lds + sc * 72 + tc * 8);
            unsigned short* dst = sk + (size_t)(sc >> 5) * SK_PIECE + pbbase
                                     + (sc & 31) * 64 + tc * 8;
            *(int4*)dst = v;
        }
    }
}

// ---- FC split-K partials: fw staged through LDS (coalesced), double-buffered
__global__ __launch_bounds__(256) void fc_part_k(
    const unsigned short* __restrict__ sk,    // in-place piece layout
    const float* __restrict__ fw,             // [256][262144] fp32, k = sc*1024+t
    float* __restrict__ part)                 // [512][64][256]
{
    __shared__ __align__(16) unsigned short blds[2][256 * 32];  // 2 x 16 KB
    int tid = threadIdx.x;
    int w = tid >> 6, lane = tid & 63;
    int quad = lane >> 4, l15 = lane & 15;
    int kb = blockIdx.x;
    int sc = kb >> 1;
    int tbase = (kb & 1) * 512;
    f32x4 zero = {0.f, 0.f, 0.f, 0.f};
    f32x4 acc[4][4];
#pragma unroll
    for (int a = 0; a < 4; ++a)
#pragma unroll
        for (int c = 0; c < 4; ++c) acc[a][c] = zero;

    const unsigned short* skp = sk + (size_t)(sc >> 5) * SK_PIECE + (sc & 31) * 64;
    const int cls_s = tid >> 3, kc_s = tid & 7;
    const float* fwbase = fw + (size_t)cls_s * 262144 + sc * 1024 + tbase + kc_s * 4;

    auto stage = [&](int it, int buf) {
        float4 v[8];
#pragma unroll
        for (int jj = 0; jj < 8; ++jj)
            v[jj] = *(const float4*)(fwbase + (size_t)jj * 32 * 262144 + it * 32);
#pragma unroll
        for (int jj = 0; jj < 8; ++jj) {
            int cls = cls_s + jj * 32;
            int slot = (kc_s >> 1) ^ (cls & 3);
            *(s4*)(blds[buf] + cls * 32 + slot * 8 + (kc_s & 1) * 4) =
                pk4_bf16(v[jj].x, v[jj].y, v[jj].z, v[jj].w);
        }
    };

    stage(0, 0);
    __syncthreads();
    for (int it = 0; it < 16; ++it) {
        int buf = it & 1;
        if (it < 15) stage(it + 1, buf ^ 1);
        int t = tbase + it * 32 + quad * 8;
        bf16x8 af[4];
#pragma unroll
        for (int rt = 0; rt < 4; ++rt) {
            int bi = rt * 16 + l15;
            af[rt] = *(const bf16x8*)(skp + (size_t)(bi * 16 + (t >> 6)) * 2048 + (t & 63));
        }
#pragma unroll
        for (int ct = 0; ct < 4; ++ct) {
            int cls = w * 64 + ct * 16 + l15;
            bf16x8 bw = *(const bf16x8*)(blds[buf] + cls * 32 + ((quad ^ (cls & 3)) * 8));
#pragma unroll
            for (int rt = 0; rt < 4; ++rt)
                acc[rt][ct] = MFMA16(af[rt], bw, acc[rt][ct]);
        }
        __syncthreads();
    }
#pragma unroll
    for (int rt = 0; rt < 4; ++rt)
#pragma unroll
        for (int ct = 0; ct < 4; ++ct)
#pragma unroll
            for (int r = 0; r < 4; ++r) {
                int bb = rt * 16 + quad * 4 + r;
                int cls = w * 64 + ct * 16 + l15;
                part[((size_t)kb * 64 + bb) * 256 + cls] = acc[rt][ct][r];
            }
}

// ---- two-stage FC reduction
__global__ void fc_r1_k(const float* __restrict__ part, float* __restrict__ part2) {
    int blk = blockIdx.x;            // 512 = 8 kc x 64 b
    int b = blk & 63, kc = blk >> 6;
    int cls = threadIdx.x;
    float s = 0.f;
    for (int kb = kc * 64; kb < kc * 64 + 64; ++kb)
        s += part[((size_t)kb * 64 + b) * 256 + cls];
    part2[((size_t)kc * 64 + b) * 256 + cls] = s;
}

__global__ void fc_r2_k(const float* __restrict__ part2,
                        const float* __restrict__ fb,
                        float* __restrict__ out) {
    int b = blockIdx.x, cls = threadIdx.x;
    float s = fb[cls];
    for (int kc = 0; kc < 8; ++kc)
        s += part2[((size_t)kc * 64 + b) * 256 + cls];
    out[b * 256 + cls] = s;
}

extern "C" void kernel_launch(void* const* d_in, const int* in_sizes, int n_in,
                              void* d_out, int out_size, void* d_ws, size_t ws_size,
                              hipStream_t stream) {
    const float* input    = (const float*)d_in[0];
    const float* start_w  = (const float*)d_in[1];
    const float* filter_w = (const float*)d_in[2];
    const float* gate_w   = (const float*)d_in[3];
    const float* res_w    = (const float*)d_in[4];
    const float* skip_w   = (const float*)d_in[5];
    const float* fc_w     = (const float*)d_in[6];
    const float* fc_b     = (const float*)d_in[7];
    float* out = (float*)d_out;

    // Overlay layout (phases A: fused rows, B: skip gemm, C: fc):
    //   [0, 160MB)        xg_all (A,B)   | sk = xg layers 0-7, in-place (B out, C in)
    //   [32MB, 64MB)      part (C)       | aliases xg layers 8-15, dead in C
    //   [64MB, +512KB)    part2 (C)      | aliases xg layers 16-..., dead in C
    //   [176MB, 176.5MB)  fgw (A)
    //   [176.5, 177.125)  swb (A write, B read)
    //   [178MB, +80KB)    rwb (A)
    const size_t REQUIRED = 192 * MB;
    if (ws_size < REQUIRED) {
        ws_probe_k<<<64, 256, 0, stream>>>(out, (float)(ws_size >> 20));
        return;
    }

    char* ws = (char*)d_ws;
    unsigned short* xg_all = (unsigned short*)(ws);             // 160MB
    unsigned short* sk     = (unsigned short*)(ws);             // 32MB in-place (B,C)
    float*          part   = (float*)(ws + 32 * MB);            // 32MB (phase C)
    float*          part2  = (float*)(ws + 64 * MB);            // 512KB (phase C)
    unsigned short* fgw    = (unsigned short*)(ws + 176 * MB);  // 480KB (phase A)
    unsigned short* swb    = (unsigned short*)(ws + 176 * MB + 512 * 1024); // 640KB (A,B)
    unsigned short* rwb    = (unsigned short*)(ws + 178 * MB);  // 80KB (phase A)

    repack_fgw_k<<<960, 256, 0, stream>>>(filter_w, gate_w, fgw);
    repack_sw_k<<<1280, 256, 0, stream>>>(skip_w, swb);
    repack_rw_k<<<160, 256, 0, stream>>>(res_w, rwb);

    wavenet_rows_k<<<64, 512, 0, stream>>>(input, start_w, fgw, rwb, xg_all);

    skip_gemm_k<<<1024, 256, 0, stream>>>(xg_all, swb, sk);
    fc_part_k<<<512, 256, 0, stream>>>(sk, fc_w, part);
    fc_r1_k<<<512, 256, 0, stream>>>(part, part2);
    fc_r2_k<<<64, 256, 0, stream>>>(part2, fc_b, out);
}

// Round 8
// 815.734 us; speedup vs baseline: 1.2571x; 1.2571x over previous
//
#include <hip/hip_runtime.h>
#include <stdint.h>

typedef short bf16x8 __attribute__((ext_vector_type(8)));
typedef short s4 __attribute__((ext_vector_type(4)));
typedef float f32x4 __attribute__((ext_vector_type(4)));

#define NPOS 65536  // B*L = 64*1024
#define MB (1024ull * 1024ull)
#define SK_PIECE 2097152  // shorts per 4MB piece of the in-place skip output

__device__ __forceinline__ unsigned short f32_bf16(float f) {
    union { float f; unsigned u; } v; v.f = f;
    unsigned u = v.u;
    u += 0x7fffu + ((u >> 16) & 1u);
    return (unsigned short)(u >> 16);
}

// 4 floats -> 4 bf16 via v_cvt_pk_bf16_f32 (RNE)
__device__ __forceinline__ s4 pk4_bf16(float a, float b, float c, float d) {
    union { unsigned u[2]; s4 v; } r;
    asm("v_cvt_pk_bf16_f32 %0, %1, %2" : "=v"(r.u[0]) : "v"(a), "v"(b));
    asm("v_cvt_pk_bf16_f32 %0, %1, %2" : "=v"(r.u[1]) : "v"(c), "v"(d));
    return r.v;
}

__device__ __forceinline__ bf16x8 pk8_bf16(const float* v) {
    union { unsigned u[4]; bf16x8 x; } r;
    asm("v_cvt_pk_bf16_f32 %0, %1, %2" : "=v"(r.u[0]) : "v"(v[0]), "v"(v[1]));
    asm("v_cvt_pk_bf16_f32 %0, %1, %2" : "=v"(r.u[1]) : "v"(v[2]), "v"(v[3]));
    asm("v_cvt_pk_bf16_f32 %0, %1, %2" : "=v"(r.u[2]) : "v"(v[4]), "v"(v[5]));
    asm("v_cvt_pk_bf16_f32 %0, %1, %2" : "=v"(r.u[3]) : "v"(v[6]), "v"(v[7]));
    return r.x;
}

// force a fragment to stay register-resident (defeats per-use rematerialization)
#define PINV(x) asm volatile("" : "+v"(x))

// fallback: encode ws_size (MiB) into output so a failing run tells us the budget
__global__ void ws_probe_k(float* __restrict__ out, float mib) {
    int i = blockIdx.x * 256 + threadIdx.x;
    if (i < 16384) out[i] = mib;
}

// ---- repack filter+gate weights -> bf16, MFMA-A rows PERMUTED so the conv
// C-fragment lands in B-fragment layout: A-row m of block mt holds
// oc = (m>>2)*8 + mt*4 + (m&3).  Blocks: rq>>4 = {f-mt0, f-mt1, g-mt0, g-mt1}.
__global__ void repack_fgw_k(const float* __restrict__ fw,
                             const float* __restrict__ gw,
                             unsigned short* __restrict__ out) {
    int idx = blockIdx.x * 256 + threadIdx.x;  // < 40*3*64*32 = 245760
    int ic = idx & 31;
    int r1 = idx >> 5;
    int rq = r1 & 63;
    int r2 = r1 >> 6;      // i*3 + k
    int k  = r2 % 3;
    int i  = r2 / 3;
    int part = rq >> 4;
    int m = rq & 15;
    int oc = ((m >> 2) << 3) + ((part & 1) << 2) + (m & 3);
    const float* src = (part < 2) ? fw : gw;
    out[idx] = f32_bf16(src[(((i * 32 + oc) * 32 + ic) * 3) + k]);
}

// ---- repack skip weights fp32 -> bf16, same layout [40][256][32]
__global__ void repack_sw_k(const float* __restrict__ sw,
                            unsigned short* __restrict__ out) {
    int idx = blockIdx.x * 256 + threadIdx.x;  // < 40*256*32 = 327680
    out[idx] = f32_bf16(sw[idx]);
}

// ---- repack residual weights -> bf16 with the same row permutation:
// A-row m of block rt holds oc = (m>>2)*8 + rt*4 + (m&3)
__global__ void repack_rw_k(const float* __restrict__ rw,
                            unsigned short* __restrict__ out) {
    int idx = blockIdx.x * 256 + threadIdx.x;  // < 40*32*32 = 40960
    int ic = idx & 31;
    int r1 = idx >> 5;
    int rq = r1 & 31;
    int i  = r1 >> 5;
    int rt = rq >> 4, m = rq & 15;
    int oc = ((m >> 2) << 3) + (rt << 2) + (m & 3);
    out[idx] = f32_bf16(rw[(i * 32 + oc) * 32 + ic]);
}

#define MFMA16(A, B, C) __builtin_amdgcn_mfma_f32_16x16x32_bf16(A, B, C, 0, 0, 0)

// ============================================================================
// Row-resident fused WaveNet v4: 64 blocks x 1024 thr (16 waves, 4 groups ea,
// 4 waves/SIMD). Grid=64 => 1 block/CU always; only waves/SIMD + VGPR
// residency matter. Double-buffered x (128KB, free at 1 block/CU) -> ONE
// barrier/layer. __launch_bounds__(1024) WITHOUT min-waves (r7 lesson: the
// min-waves hint forced a 64-VGPR allocation and remat'd the weights onto
// the critical path). Weight fragments pinned via empty inline asm inside
// the group loop so they cannot be rematerialized per use.
// ============================================================================
__global__ __launch_bounds__(1024) void wavenet_rows_k(
    const float* __restrict__ in,               // [64][2][1024]
    const float* __restrict__ stw,              // [32][2]
    const unsigned short* __restrict__ fgw_all, // [40][3][64][32] permuted
    const unsigned short* __restrict__ rwb_all, // [40][32][32] permuted
    unsigned short* __restrict__ xg_all)        // [40][65536][32] bf16
{
    __shared__ __align__(16) unsigned short xb16[2][1024 * 32];  // 128 KB
    const int tid = threadIdx.x;
    const int w = tid >> 6, lane = tid & 63;
    const int quad = lane >> 4, l15 = lane & 15;
    const int b = blockIdx.x;
    const f32x4 zero = {0.f, 0.f, 0.f, 0.f};

    float xreg[4][8];   // ch = quad*8 + j at pos (w*4+g)*16 + l15

    // ---- start conv (2 -> 32 ch) into registers + LDS buf 0
    {
        float s0[8], s1[8];
#pragma unroll
        for (int j = 0; j < 8; ++j) {
            int c = quad * 8 + j;
            s0[j] = stw[c * 2 + 0];
            s1[j] = stw[c * 2 + 1];
        }
#pragma unroll
        for (int g = 0; g < 4; ++g) {
            int t = (w * 4 + g) * 16 + l15;
            float i0 = in[b * 2048 + t];
            float i1 = in[b * 2048 + 1024 + t];
#pragma unroll
            for (int j = 0; j < 8; ++j) xreg[g][j] = s0[j] * i0 + s1[j] * i1;
            *(bf16x8*)(xb16[0] + t * 32 + ((quad ^ (t & 3)) * 8)) = pk8_bf16(xreg[g]);
        }
    }
    __syncthreads();

#pragma unroll 1
    for (int i = 0; i < 40; ++i) {
        const int d = 1 << (i % 10);
        const unsigned short* fgw = fgw_all + (size_t)i * 6144;
        unsigned short* xg = xg_all + (size_t)i * ((size_t)NPOS * 32)
                                    + (size_t)b * (1024 * 32);
        const unsigned short* xcur = xb16[i & 1];
        unsigned short* xnxt = xb16[(i & 1) ^ 1];
        const bool dores = (i < 39);

        // preload weights (L2-hot) once per layer
        bf16x8 wf[3][2], wg[3][2];
#pragma unroll
        for (int k = 0; k < 3; ++k) {
            const unsigned short* wb = fgw + k * 2048;
#pragma unroll
            for (int mt = 0; mt < 2; ++mt) {
                wf[k][mt] = *(const bf16x8*)(wb + (mt * 16 + l15) * 32 + quad * 8);
                wg[k][mt] = *(const bf16x8*)(wb + ((mt + 2) * 16 + l15) * 32 + quad * 8);
            }
        }
        bf16x8 wr0, wr1;
        if (dores) {
            const unsigned short* rwb = rwb_all + (size_t)i * 1024;
            wr0 = *(const bf16x8*)(rwb + l15 * 32 + quad * 8);
            wr1 = *(const bf16x8*)(rwb + (16 + l15) * 32 + quad * 8);
        } else {
            wr0 = bf16x8{0,0,0,0,0,0,0,0};
            wr1 = bf16x8{0,0,0,0,0,0,0,0};
        }

#pragma unroll
        for (int g = 0; g < 4; ++g) {
            // pin: redefine the fragments each iteration -> no remat per use
#pragma unroll
            for (int k = 0; k < 3; ++k) {
                PINV(wf[k][0]); PINV(wf[k][1]);
                PINV(wg[k][0]); PINV(wg[k][1]);
            }
            PINV(wr0); PINV(wr1);

            const int tc = (w * 4 + g) * 16 + l15;

            bf16x8 zz;
#pragma unroll
            for (int j = 0; j < 8; ++j) zz[j] = 0;

            f32x4 accf[2] = {zero, zero};
            f32x4 accg[2] = {zero, zero};
            {   // left tap
                int ts = tc - d, tm = ts & 1023;
                bf16x8 rv = *(const bf16x8*)(xcur + tm * 32 + ((quad ^ (tm & 3)) * 8));
                bf16x8 b0 = (ts >= 0) ? rv : zz;
#pragma unroll
                for (int mt = 0; mt < 2; ++mt) {
                    accf[mt] = MFMA16(wf[0][mt], b0, accf[mt]);
                    accg[mt] = MFMA16(wg[0][mt], b0, accg[mt]);
                }
            }
            {   // center tap
                bf16x8 b1 = *(const bf16x8*)(xcur + tc * 32 + ((quad ^ (tc & 3)) * 8));
#pragma unroll
                for (int mt = 0; mt < 2; ++mt) {
                    accf[mt] = MFMA16(wf[1][mt], b1, accf[mt]);
                    accg[mt] = MFMA16(wg[1][mt], b1, accg[mt]);
                }
            }
            {   // right tap
                int ts = tc + d, tm = ts & 1023;
                bf16x8 rv = *(const bf16x8*)(xcur + tm * 32 + ((quad ^ (tm & 3)) * 8));
                bf16x8 b2 = (ts < 1024) ? rv : zz;
#pragma unroll
                for (int mt = 0; mt < 2; ++mt) {
                    accf[mt] = MFMA16(wf[2][mt], b2, accf[mt]);
                    accg[mt] = MFMA16(wg[2][mt], b2, accg[mt]);
                }
            }

            // gating: tanh(f)*sigmoid(g) = (a-1) * rcp((a+1)(1+c)), 3 trans
            float gv[8];
#pragma unroll
            for (int mt = 0; mt < 2; ++mt)
#pragma unroll
                for (int r = 0; r < 4; ++r) {
                    float fv = accf[mt][r], gg = accg[mt][r];
                    fv = fminf(fmaxf(fv, -10.f), 10.f);
                    gg = fminf(fmaxf(gg, -15.f), 15.f);
                    float a = __expf(2.f * fv);
                    float c = __expf(-gg);
                    float rr = __builtin_amdgcn_rcpf((a + 1.f) * (1.f + c));
                    gv[mt * 4 + r] = (a - 1.f) * rr;
                }
            bf16x8 bx = pk8_bf16(gv);   // == xg fragment AND res-B fragment

            // coalesced register->global xg store (wave tiles 16pos x 32ch)
            *(bf16x8*)(xg + (size_t)tc * 32 + quad * 8) = bx;

            if (dores) {
                f32x4 a0 = MFMA16(wr0, bx, zero);
                f32x4 a1 = MFMA16(wr1, bx, zero);
#pragma unroll
                for (int r = 0; r < 4; ++r) {
                    xreg[g][r]     += a0[r];
                    xreg[g][4 + r] += a1[r];
                }
                // publish new x to the other buffer (no WAR: reads from xcur)
                int t = tc;
                *(bf16x8*)(xnxt + t * 32 + ((quad ^ (t & 3)) * 8)) = pk8_bf16(xreg[g]);
            }
        }
        __syncthreads();   // xnxt complete before next layer reads it
    }
}

// ============================================================================
// skip GEMM v5: B tile staged once per block via global_load_lds (16B), LDS
// double-buffered, slot-swizzled on the GLOBAL SOURCE (inverse of the read
// swizzle) so ds_read_b128 fragment reads are <=2-way bank aliased.
// A (weights) 1-deep register prefetch from L2. XCD-aware block swizzle.
// Output in-place piece layout (unchanged).
// ============================================================================
__global__ __launch_bounds__(256) void skip_gemm_k(
    const unsigned short* __restrict__ xg_all,  // [40][65536][32] bf16
    const unsigned short* __restrict__ swb,     // [40][256][32] bf16
    unsigned short* __restrict__ sk)            // == xg_all base (in-place)
{
    __shared__ __align__(16) unsigned short lds[256 * 72];  // 36 KB; first 4096
                                                            // shorts = 2 B-bufs
    int tid = threadIdx.x;
    int w = tid >> 6, lane = tid & 63;
    int quad = lane >> 4, l15 = lane & 15;
    int pb = (blockIdx.x & 7) * 128 + (blockIdx.x >> 3);   // bijective (1024%8==0)
    int p0 = pb * 64;
    f32x4 zero = {0.f, 0.f, 0.f, 0.f};
    f32x4 acc[4][4];
#pragma unroll
    for (int a = 0; a < 4; ++a)
#pragma unroll
        for (int c = 0; c < 4; ++c) acc[a][c] = zero;

    // staging: slot s (=tid) holds tile unit u = s ^ ((s>>3)&7)  (involution)
    const int gswz = tid ^ ((tid >> 3) & 7);
    // reader: frag (ct,lane): u = (ct*16+l15)*4+quad; slot = u ^ ((u>>3)&7)
    int rslot[4];
#pragma unroll
    for (int ct = 0; ct < 4; ++ct) {
        int u = (ct * 16 + l15) * 4 + quad;
        rslot[ct] = u ^ ((u >> 3) & 7);
    }

    const unsigned short* abase = swb + ((size_t)(w * 64 + l15)) * 32 + quad * 8;

    auto stage = [&](int i, int s) {
        const unsigned short* g = xg_all + ((size_t)i * NPOS + p0) * 32 + gswz * 8;
        unsigned short* l = lds + s * 2048 + w * 512;
        __builtin_amdgcn_global_load_lds(
            (const __attribute__((address_space(1))) unsigned int*)g,
            (__attribute__((address_space(3))) unsigned int*)l, 16, 0, 0);
    };

    stage(0, 0);
    bf16x8 acur[4], anxt[4];
#pragma unroll
    for (int rt = 0; rt < 4; ++rt) acur[rt] = *(const bf16x8*)(abase + rt * 512);

#pragma unroll 2
    for (int i = 0; i < 40; ++i) {
        int cb = i & 1;
        __syncthreads();   // stage(i) landed (vmcnt drained) + old readers done
        if (i + 1 < 40) {
            stage(i + 1, cb ^ 1);
            const unsigned short* an = abase + (size_t)(i + 1) * 8192;
#pragma unroll
            for (int rt = 0; rt < 4; ++rt) anxt[rt] = *(const bf16x8*)(an + rt * 512);
        }
        const unsigned short* bufc = lds + cb * 2048;
        bf16x8 bfr[4];
#pragma unroll
        for (int ct = 0; ct < 4; ++ct) bfr[ct] = *(const bf16x8*)(bufc + rslot[ct] * 8);
#pragma unroll
        for (int rt = 0; rt < 4; ++rt)
#pragma unroll
            for (int ct = 0; ct < 4; ++ct)
                acc[rt][ct] = MFMA16(acur[rt], bfr[ct], acc[rt][ct]);
#pragma unroll
        for (int rt = 0; rt < 4; ++rt) acur[rt] = anxt[rt];
    }

    __syncthreads();   // all waves done with B bufs before epilogue overwrites
#pragma unroll
    for (int rt = 0; rt < 4; ++rt)
#pragma unroll
        for (int ct = 0; ct < 4; ++ct)
#pragma unroll
            for (int r = 0; r < 4; ++r) {
                float v = acc[rt][ct][r];
                v = v > 0.f ? v : 0.f;
                lds[(w * 64 + rt * 16 + quad * 4 + r) * 72 + ct * 16 + l15] = f32_bf16(v);
            }
    __syncthreads();
    {
        size_t pbbase = (size_t)pb * 2048;
#pragma unroll
        for (int j = 0; j < 8; ++j) {
            int idx = tid + 256 * j;      // 2048 16B chunks
            int sc = idx >> 3, tc = idx & 7;
            int4 v = *(const int4*)(lds + sc * 72 + tc * 8);
            unsigned short* dst = sk + (size_t)(sc >> 5) * SK_PIECE + pbbase
                                     + (sc & 31) * 64 + tc * 8;
            *(int4*)dst = v;
        }
    }
}

// ---- FC split-K partials: fw staged through LDS (coalesced), double-buffered
__global__ __launch_bounds__(256) void fc_part_k(
    const unsigned short* __restrict__ sk,    // in-place piece layout
    const float* __restrict__ fw,             // [256][262144] fp32, k = sc*1024+t
    float* __restrict__ part)                 // [512][64][256]
{
    __shared__ __align__(16) unsigned short blds[2][256 * 32];  // 2 x 16 KB
    int tid = threadIdx.x;
    int w = tid >> 6, lane = tid & 63;
    int quad = lane >> 4, l15 = lane & 15;
    int kb = blockIdx.x;
    int sc = kb >> 1;
    int tbase = (kb & 1) * 512;
    f32x4 zero = {0.f, 0.f, 0.f, 0.f};
    f32x4 acc[4][4];
#pragma unroll
    for (int a = 0; a < 4; ++a)
#pragma unroll
        for (int c = 0; c < 4; ++c) acc[a][c] = zero;

    const unsigned short* skp = sk + (size_t)(sc >> 5) * SK_PIECE + (sc & 31) * 64;
    const int cls_s = tid >> 3, kc_s = tid & 7;
    const float* fwbase = fw + (size_t)cls_s * 262144 + sc * 1024 + tbase + kc_s * 4;

    auto stage = [&](int it, int buf) {
        float4 v[8];
#pragma unroll
        for (int jj = 0; jj < 8; ++jj)
            v[jj] = *(const float4*)(fwbase + (size_t)jj * 32 * 262144 + it * 32);
#pragma unroll
        for (int jj = 0; jj < 8; ++jj) {
            int cls = cls_s + jj * 32;
            int slot = (kc_s >> 1) ^ (cls & 3);
            *(s4*)(blds[buf] + cls * 32 + slot * 8 + (kc_s & 1) * 4) =
                pk4_bf16(v[jj].x, v[jj].y, v[jj].z, v[jj].w);
        }
    };

    stage(0, 0);
    __syncthreads();
    for (int it = 0; it < 16; ++it) {
        int buf = it & 1;
        if (it < 15) stage(it + 1, buf ^ 1);
        int t = tbase + it * 32 + quad * 8;
        bf16x8 af[4];
#pragma unroll
        for (int rt = 0; rt < 4; ++rt) {
            int bi = rt * 16 + l15;
            af[rt] = *(const bf16x8*)(skp + (size_t)(bi * 16 + (t >> 6)) * 2048 + (t & 63));
        }
#pragma unroll
        for (int ct = 0; ct < 4; ++ct) {
            int cls = w * 64 + ct * 16 + l15;
            bf16x8 bw = *(const bf16x8*)(blds[buf] + cls * 32 + ((quad ^ (cls & 3)) * 8));
#pragma unroll
            for (int rt = 0; rt < 4; ++rt)
                acc[rt][ct] = MFMA16(af[rt], bw, acc[rt][ct]);
        }
        __syncthreads();
    }
#pragma unroll
    for (int rt = 0; rt < 4; ++rt)
#pragma unroll
        for (int ct = 0; ct < 4; ++ct)
#pragma unroll
            for (int r = 0; r < 4; ++r) {
                int bb = rt * 16 + quad * 4 + r;
                int cls = w * 64 + ct * 16 + l15;
                part[((size_t)kb * 64 + bb) * 256 + cls] = acc[rt][ct][r];
            }
}

// ---- two-stage FC reduction
__global__ void fc_r1_k(const float* __restrict__ part, float* __restrict__ part2) {
    int blk = blockIdx.x;            // 512 = 8 kc x 64 b
    int b = blk & 63, kc = blk >> 6;
    int cls = threadIdx.x;
    float s = 0.f;
    for (int kb = kc * 64; kb < kc * 64 + 64; ++kb)
        s += part[((size_t)kb * 64 + b) * 256 + cls];
    part2[((size_t)kc * 64 + b) * 256 + cls] = s;
}

__global__ void fc_r2_k(const float* __restrict__ part2,
                        const float* __restrict__ fb,
                        float* __restrict__ out) {
    int b = blockIdx.x, cls = threadIdx.x;
    float s = fb[cls];
    for (int kc = 0; kc < 8; ++kc)
        s += part2[((size_t)kc * 64 + b) * 256 + cls];
    out[b * 256 + cls] = s;
}

extern "C" void kernel_launch(void* const* d_in, const int* in_sizes, int n_in,
                              void* d_out, int out_size, void* d_ws, size_t ws_size,
                              hipStream_t stream) {
    const float* input    = (const float*)d_in[0];
    const float* start_w  = (const float*)d_in[1];
    const float* filter_w = (const float*)d_in[2];
    const float* gate_w   = (const float*)d_in[3];
    const float* res_w    = (const float*)d_in[4];
    const float* skip_w   = (const float*)d_in[5];
    const float* fc_w     = (const float*)d_in[6];
    const float* fc_b     = (const float*)d_in[7];
    float* out = (float*)d_out;

    // Overlay layout (phases A: fused rows, B: skip gemm, C: fc):
    //   [0, 160MB)        xg_all (A,B)   | sk = xg layers 0-7, in-place (B out, C in)
    //   [32MB, 64MB)      part (C)       | aliases xg layers 8-15, dead in C
    //   [64MB, +512KB)    part2 (C)      | aliases xg layers 16-..., dead in C
    //   [176MB, 176.5MB)  fgw (A)
    //   [176.5, 177.125)  swb (A write, B read)
    //   [178MB, +80KB)    rwb (A)
    const size_t REQUIRED = 192 * MB;
    if (ws_size < REQUIRED) {
        ws_probe_k<<<64, 256, 0, stream>>>(out, (float)(ws_size >> 20));
        return;
    }

    char* ws = (char*)d_ws;
    unsigned short* xg_all = (unsigned short*)(ws);             // 160MB
    unsigned short* sk     = (unsigned short*)(ws);             // 32MB in-place (B,C)
    float*          part   = (float*)(ws + 32 * MB);            // 32MB (phase C)
    float*          part2  = (float*)(ws + 64 * MB);            // 512KB (phase C)
    unsigned short* fgw    = (unsigned short*)(ws + 176 * MB);  // 480KB (phase A)
    unsigned short* swb    = (unsigned short*)(ws + 176 * MB + 512 * 1024); // 640KB (A,B)
    unsigned short* rwb    = (unsigned short*)(ws + 178 * MB);  // 80KB (phase A)

    repack_fgw_k<<<960, 256, 0, stream>>>(filter_w, gate_w, fgw);
    repack_sw_k<<<1280, 256, 0, stream>>>(skip_w, swb);
    repack_rw_k<<<160, 256, 0, stream>>>(res_w, rwb);

    wavenet_rows_k<<<64, 1024, 0, stream>>>(input, start_w, fgw, rwb, xg_all);

    skip_gemm_k<<<1024, 256, 0, stream>>>(xg_all, swb, sk);
    fc_part_k<<<512, 256, 0, stream>>>(sk, fc_w, part);
    fc_r1_k<<<512, 256, 0, stream>>>(part, part2);
    fc_r2_k<<<64, 256, 0, stream>>>(part2, fc_b, out);
}